// Round 12
// baseline (164.618 us; speedup 1.0000x reference)
//
#include <hip/hip_runtime.h>
#include <hip/hip_bf16.h>
#include <cstdint>

#define NPTS 4096
#define NB 8
#define KNN 20
#define CAP 32          // collected-candidate capacity (typ n ~21-26)
#define NW 12           // waves per block (768 threads)

__device__ __forceinline__ float lrelu(float x) { return x >= 0.0f ? x : 0.2f * x; }

// monotone float<->uint mapping (order-preserving for all finite floats)
__device__ __forceinline__ uint32_t enc_f32(float f) {
    uint32_t u = __float_as_uint(f);
    return (u & 0x80000000u) ? ~u : (u | 0x80000000u);
}
__device__ __forceinline__ float dec_f32(uint32_t u) {
    return (u & 0x80000000u) ? __uint_as_float(u ^ 0x80000000u) : __uint_as_float(~u);
}

// XOR bank swizzle (verified R8: bank conflicts 110K -> 0 in both patterns)
__device__ __forceinline__ int physidx(int i) {
    return (i & ~63) | ((i ^ (i >> 6)) & 63);
}

// ---------------------------------------------------------------------------
// K1: fused kNN (top-20 smallest sq-dist, ties -> smaller index) + EdgeConv
//     (6->64) + max over k.  768-thr blocks (12 waves) sharing one 64 KB pts
//     tile -> 2 blocks/CU = 6 waves/SIMD (R11 had 4).  8 rows/wave.
//     P1: per-lane top-2 u-values (3 fma + fmed3 + fmax per candidate)
//     P2: 16-bit radix-ballot -> theta~ <= true 20th value (2 halves x 4 rows)
//     P3: cooperative collect u >= theta~ ; exact rank if n > 20 (rank output
//         aliased into cval -- wave-lockstep makes read-before-write safe).
// ---------------------------------------------------------------------------
__global__ __launch_bounds__(768, 6) void k1_knn_edge(
        const float* __restrict__ x,
        const float* __restrict__ W0, const float* __restrict__ b0,
        const float* __restrict__ s0, const float* __restrict__ t0,
        float* __restrict__ H0)
{
    __shared__ float4 pts[NPTS];          // 64 KB, swizzled, (2x,2y,2z,-|p|^2)
    __shared__ float  cval[NW][4][CAP];   // 6 KB  (reused as int sel[] after rank)
    __shared__ int    cidx[NW][4][CAP];   // 6 KB
    __shared__ float  sW0[64 * 6];
    __shared__ float  sB[64], sS[64], sT[64];

    const int blk = blockIdx.x;
    const int b = blk / 43;               // 43 blocks per batch
    const int rowbase = (blk % 43) * 96;  // 96 rows per block (12 waves x 8)
    const int t = threadIdx.x;
    const int lane = t & 63;
    const int w = t >> 6;                 // wave 0..11

    const float* xb = x + (size_t)b * (NPTS * 3);

    // ---- single staging of all 4096 points ----
    for (int i = t; i < NPTS; i += 768) {
        float x0 = xb[3 * i], x1 = xb[3 * i + 1], x2 = xb[3 * i + 2];
        float pp = __fadd_rn(__fadd_rn(__fmul_rn(x0, x0), __fmul_rn(x1, x1)),
                             __fmul_rn(x2, x2));
        pts[physidx(i)] = make_float4(x0 + x0, x1 + x1, x2 + x2, -pp);
    }
    if (t < 64) {
        #pragma unroll
        for (int c = 0; c < 6; c++) sW0[t * 6 + c] = W0[t * 6 + c];
        sB[t] = b0[t]; sS[t] = s0[t]; sT[t] = t0[t];
    }
    __syncthreads();

    const int r0 = rowbase + w * 8;
    if (r0 >= NPTS) return;               // idle waves in the last block/batch

    float qx[8], qy[8], qz[8];
    #pragma unroll
    for (int rr = 0; rr < 8; rr++) {
        qx[rr] = xb[3 * (r0 + rr) + 0];
        qy[rr] = xb[3 * (r0 + rr) + 1];
        qz[rr] = xb[3 * (r0 + rr) + 2];
    }

    // ---- P1: per-lane top-2 values for 8 rows ----
    float l0[8], l1[8];
    #pragma unroll
    for (int rr = 0; rr < 8; rr++) { l0[rr] = -INFINITY; l1[rr] = -INFINITY; }

    #pragma unroll 4
    for (int j = 0; j < 64; j++) {
        const float4 p = pts[(j << 6) | ((lane ^ j) & 63)];
        #pragma unroll
        for (int rr = 0; rr < 8; rr++) {
            float u = fmaf(qx[rr], p.x, fmaf(qy[rr], p.y, fmaf(qz[rr], p.z, p.w)));
            l1[rr] = __builtin_amdgcn_fmed3f(u, l0[rr], l1[rr]);  // new top-2
            l0[rr] = fmaxf(u, l0[rr]);                            // new top-1
        }
    }

    const float wa0 = sW0[lane * 6 + 0], wa1 = sW0[lane * 6 + 1], wa2 = sW0[lane * 6 + 2];
    const float wa0h = 0.5f * wa0, wa1h = 0.5f * wa1, wa2h = 0.5f * wa2;  // pts hold 2p
    const float wd0 = sW0[lane * 6 + 3] - wa0;
    const float wd1 = sW0[lane * 6 + 4] - wa1;
    const float wd2 = sW0[lane * 6 + 5] - wa2;

    // ---- process rows in two halves of 4 (keeps collect-LDS small) ----
    for (int half = 0; half < 2; half++) {
        const int R = half * 4;

        // P2: 16-bit radix-ballot theta~ (bits 31..16 of enc).
        uint32_t e0[4], e1[4], pr[4];
        #pragma unroll
        for (int rr = 0; rr < 4; rr++) {
            e0[rr] = enc_f32(l0[R + rr]);
            e1[rr] = enc_f32(l1[R + rr]);
            pr[rr] = 0u;
        }
        for (int bit = 31; bit >= 16; bit--) {
            #pragma unroll
            for (int rr = 0; rr < 4; rr++) {
                uint32_t T = pr[rr] | (1u << bit);
                int c = __popcll(__ballot(e0[rr] >= T)) + __popcll(__ballot(e1[rr] >= T));
                if (c >= KNN) pr[rr] = T;     // wave-uniform
            }
        }
        float th[4];
        #pragma unroll
        for (int rr = 0; rr < 4; rr++) th[rr] = dec_f32(pr[rr]);

        // P3a: collect all u >= theta~ via cooperative lane-rescans.
        int nsel[4];
        #pragma unroll
        for (int rr = 0; rr < 4; rr++) {
            int base = 0;
            unsigned long long lm = __ballot(l0[R + rr] >= th[rr]);
            while (lm) {
                int L = __ffsll(lm) - 1; lm &= lm - 1;          // uniform
                const float4 p = pts[(lane << 6) | ((L ^ lane) & 63)];
                float u = fmaf(qx[R + rr], p.x,
                          fmaf(qy[R + rr], p.y, fmaf(qz[R + rr], p.z, p.w)));
                unsigned long long hit = __ballot(u >= th[rr]);
                if (u >= th[rr]) {
                    int pos = base + __popcll(hit & ((1ull << lane) - 1ull));
                    if (pos < CAP) {
                        cval[w][rr][pos] = u;
                        cidx[w][rr][pos] = (lane << 6) | L;
                    }
                }
                base += __popcll(hit);
            }
            nsel[rr] = min(base, CAP);
        }

        // P3b: exact top-20 by (value desc, idx asc) when n > 20.
        // Rank output written into cval's storage (int view).  Safe: the whole
        // wave's f-loop reads issue before the write instruction (lockstep).
        #pragma unroll
        for (int rr = 0; rr < 4; rr++) {
            int n = nsel[rr];
            if (n > KNN) {                    // wave-uniform branch
                bool act = lane < n;
                float ve = act ? cval[w][rr][lane] : -INFINITY;
                int   ie = act ? cidx[w][rr][lane] : 0x7FFFFFFF;
                int rk = 0;
                for (int f = 0; f < n; f++) {
                    float vf = cval[w][rr][f];
                    int   if_ = cidx[w][rr][f];
                    rk += ((vf > ve) || (vf == ve && if_ < ie)) ? 1 : 0;
                }
                int* selp = (int*)cval[w][rr];
                if (act && rk < KNN) selp[rk] = ie;
            }
        }

        // P3c: consume -- per-channel (lane) max over selected neighbors
        #pragma unroll
        for (int rr = 0; rr < 4; rr++) {
            int n = nsel[rr];
            bool ranked = n > KNN;
            int cnt20 = ranked ? KNN : n;
            const int* selp = (const int*)cval[w][rr];
            float mm = -INFINITY;
            for (int e = 0; e < cnt20; e++) {
                int g = ranked ? selp[e] : cidx[w][rr][e];   // uniform -> broadcast
                float4 p = pts[physidx(g)];
                float dotp = fmaf(wa2h, p.z, fmaf(wa1h, p.y, wa0h * p.x));
                mm = fmaxf(mm, dotp);
            }
            // conv = max_k(W0a.p_k) + (W0b-W0a).q ; (conv+b)*s+t ; lrelu.
            // s0>0 and lrelu monotone => max commutes past affine+activation.
            float cterm = fmaf(wd2, qz[R + rr], fmaf(wd1, qy[R + rr], wd0 * qx[R + rr]));
            float z = (mm + cterm + sB[lane]) * sS[lane] + sT[lane];
            H0[((size_t)(b * NPTS) + r0 + R + rr) * 64 + lane] = lrelu(z);
        }
    }
}

// ---------------------------------------------------------------------------
// K2: pconv chain 64->64->128->128 + max over points.  1024 blocks x 128 thr,
//     4 points per thread (R9 verbatim -- measured best).  Weights from
//     global (L2-cached, og-group lanes share addresses); h tiles in LDS.
//     Thread = (ps 0..7, og 0..15); points {ps, ps+8, ps+16, ps+24}.
// ---------------------------------------------------------------------------
__global__ __launch_bounds__(128, 2) void k2_mlp(
        const float* __restrict__ H0,
        const float* __restrict__ W1, const float* __restrict__ b1,
        const float* __restrict__ s1, const float* __restrict__ t1,
        const float* __restrict__ W2, const float* __restrict__ b2,
        const float* __restrict__ s2, const float* __restrict__ t2,
        const float* __restrict__ W3, const float* __restrict__ b3,
        const float* __restrict__ s3, const float* __restrict__ t3,
        uint32_t* __restrict__ gmax)
{
    __shared__ float A[32 * 132];     // h0 (64c) then aliased h2 (128c), stride 132
    __shared__ float h1[32 * 68];     // stride 68
    __shared__ uint32_t bmax[128];

    const int t = threadIdx.x;            // 128 threads
    const int blk = blockIdx.x;
    const int b = blk >> 7;               // 128 blocks per batch
    const int pbase = (blk & 127) * 32;   // 32 points per block

    const int ps = t & 7;                 // 0..7
    const int og = t >> 3;                // 0..15

    // stage h0 tile [32 pts][64 ch] -> A (stride 132): 512 float4, 4/thread
    {
        const float4* src = (const float4*)&H0[((size_t)(b * NPTS) + pbase) * 64];
        #pragma unroll
        for (int k = 0; k < 4; k++) {
            int i4 = t * 4 + k;
            int p = i4 >> 4, c = (i4 & 15) * 4;
            *(float4*)&A[p * 132 + c] = src[i4];
        }
    }
    bmax[t] = 0u;
    __syncthreads();

    // ---- L1: 64 -> 64 ; outs o = og*4+[0,4), pts {ps+8*pp} ----
    {
        float acc[4][4] = {};
        for (int c = 0; c < 64; c += 4) {
            float4 h[4];
            #pragma unroll
            for (int pp = 0; pp < 4; pp++)
                h[pp] = *(const float4*)&A[(ps + 8 * pp) * 132 + c];
            #pragma unroll
            for (int r = 0; r < 4; r++) {
                float4 wv = *(const float4*)&W1[(og * 4 + r) * 64 + c];
                #pragma unroll
                for (int pp = 0; pp < 4; pp++)
                    acc[pp][r] += h[pp].x * wv.x + h[pp].y * wv.y
                                + h[pp].z * wv.z + h[pp].w * wv.w;
            }
        }
        #pragma unroll
        for (int pp = 0; pp < 4; pp++) {
            float4 o4; float* po = (float*)&o4;
            #pragma unroll
            for (int r = 0; r < 4; r++) {
                int o = og * 4 + r;
                po[r] = lrelu((acc[pp][r] + b1[o]) * s1[o] + t1[o]);
            }
            *(float4*)&h1[(ps + 8 * pp) * 68 + og * 4] = o4;
        }
    }
    __syncthreads();

    // ---- L2: 64 -> 128 ; outs o = og*8+[0,8) ; h2 overwrites A ----
    {
        float acc[4][8] = {};
        for (int c = 0; c < 64; c += 4) {
            float4 h[4];
            #pragma unroll
            for (int pp = 0; pp < 4; pp++)
                h[pp] = *(const float4*)&h1[(ps + 8 * pp) * 68 + c];
            #pragma unroll
            for (int r = 0; r < 8; r++) {
                float4 wv = *(const float4*)&W2[(og * 8 + r) * 64 + c];
                #pragma unroll
                for (int pp = 0; pp < 4; pp++)
                    acc[pp][r] += h[pp].x * wv.x + h[pp].y * wv.y
                                + h[pp].z * wv.z + h[pp].w * wv.w;
            }
        }
        __syncthreads();   // everyone done reading A (h0) before overwriting
        #pragma unroll
        for (int pp = 0; pp < 4; pp++) {
            float4 o4a, o4b; float* pa = (float*)&o4a; float* pb = (float*)&o4b;
            #pragma unroll
            for (int r = 0; r < 4; r++) {
                int o = og * 8 + r;
                pa[r] = lrelu((acc[pp][r] + b2[o]) * s2[o] + t2[o]);
            }
            #pragma unroll
            for (int r = 4; r < 8; r++) {
                int o = og * 8 + r;
                pb[r - 4] = lrelu((acc[pp][r] + b2[o]) * s2[o] + t2[o]);
            }
            *(float4*)&A[(ps + 8 * pp) * 132 + og * 8]     = o4a;
            *(float4*)&A[(ps + 8 * pp) * 132 + og * 8 + 4] = o4b;
        }
    }
    __syncthreads();

    // ---- L3: 128 -> 128 + max over points ----
    {
        float acc[4][8] = {};
        for (int c = 0; c < 128; c += 4) {
            float4 h[4];
            #pragma unroll
            for (int pp = 0; pp < 4; pp++)
                h[pp] = *(const float4*)&A[(ps + 8 * pp) * 132 + c];
            #pragma unroll
            for (int r = 0; r < 8; r++) {
                float4 wv = *(const float4*)&W3[(og * 8 + r) * 128 + c];
                #pragma unroll
                for (int pp = 0; pp < 4; pp++)
                    acc[pp][r] += h[pp].x * wv.x + h[pp].y * wv.y
                                + h[pp].z * wv.z + h[pp].w * wv.w;
            }
        }
        // max over own 4 points (pre-affine: s3>0, monotone), then across ps
        float m[8];
        #pragma unroll
        for (int r = 0; r < 8; r++)
            m[r] = fmaxf(fmaxf(acc[0][r], acc[1][r]), fmaxf(acc[2][r], acc[3][r]));
        #pragma unroll
        for (int off = 1; off < 8; off <<= 1) {
            #pragma unroll
            for (int r = 0; r < 8; r++)
                m[r] = fmaxf(m[r], __shfl_xor(m[r], off));
        }
        if (ps == 0) {
            #pragma unroll
            for (int r = 0; r < 8; r++) {
                int o = og * 8 + r;
                float z = lrelu((m[r] + b3[o]) * s3[o] + t3[o]);
                atomicMax(&bmax[o], enc_f32(z));
            }
        }
    }
    __syncthreads();
    atomicMax(&gmax[b * 128 + t], bmax[t]);
}

// ---------------------------------------------------------------------------
// K3: head 128 -> 512 (affine+lrelu) -> 1024.  64 blocks (8 batch x 8 chunk).
// ---------------------------------------------------------------------------
__global__ __launch_bounds__(256) void k3_head(
        const uint32_t* __restrict__ gmax,
        const float* __restrict__ W4, const float* __restrict__ b4,
        const float* __restrict__ s4, const float* __restrict__ t4,
        const float* __restrict__ W5, const float* __restrict__ b5,
        float* __restrict__ out)
{
    __shared__ float sIn[128];
    __shared__ float sH4[512];
    const int t = threadIdx.x;
    const int b = blockIdx.x >> 3;
    const int chunk = blockIdx.x & 7;

    if (t < 128) sIn[t] = dec_f32(gmax[b * 128 + t]);
    __syncthreads();

    #pragma unroll
    for (int rep = 0; rep < 2; rep++) {
        int o = t + rep * 256;
        const float4* wr = (const float4*)&W4[(size_t)o * 128];
        float acc = 0.f;
        for (int c4 = 0; c4 < 32; c4++) {
            float4 wv = wr[c4];
            acc += sIn[c4 * 4] * wv.x + sIn[c4 * 4 + 1] * wv.y
                 + sIn[c4 * 4 + 2] * wv.z + sIn[c4 * 4 + 3] * wv.w;
        }
        float z = (acc + b4[o]) * s4[o] + t4[o];
        sH4[o] = lrelu(z);
    }
    __syncthreads();

    if (t < 128) {
        int o = chunk * 128 + t;
        const float4* wr = (const float4*)&W5[(size_t)o * 512];
        float acc = 0.f;
        for (int c4 = 0; c4 < 128; c4++) {
            float4 wv = wr[c4];
            acc += sH4[c4 * 4] * wv.x + sH4[c4 * 4 + 1] * wv.y
                 + sH4[c4 * 4 + 2] * wv.z + sH4[c4 * 4 + 3] * wv.w;
        }
        out[(size_t)b * 1024 + o] = acc + b5[o];
    }
}

// ---------------------------------------------------------------------------
extern "C" void kernel_launch(void* const* d_in, const int* in_sizes, int n_in,
                              void* d_out, int out_size, void* d_ws, size_t ws_size,
                              hipStream_t stream) {
    (void)in_sizes; (void)n_in; (void)out_size; (void)ws_size;
    const float* x  = (const float*)d_in[0];
    const float* W0 = (const float*)d_in[1];
    const float* b0 = (const float*)d_in[2];
    const float* s0 = (const float*)d_in[3];
    const float* t0 = (const float*)d_in[4];
    const float* W1 = (const float*)d_in[5];
    const float* b1 = (const float*)d_in[6];
    const float* s1 = (const float*)d_in[7];
    const float* t1 = (const float*)d_in[8];
    const float* W2 = (const float*)d_in[9];
    const float* b2 = (const float*)d_in[10];
    const float* s2 = (const float*)d_in[11];
    const float* t2 = (const float*)d_in[12];
    const float* W3 = (const float*)d_in[13];
    const float* b3 = (const float*)d_in[14];
    const float* s3 = (const float*)d_in[15];
    const float* t3 = (const float*)d_in[16];
    const float* W4 = (const float*)d_in[17];
    const float* b4 = (const float*)d_in[18];
    const float* s4 = (const float*)d_in[19];
    const float* t4 = (const float*)d_in[20];
    const float* W5 = (const float*)d_in[21];
    const float* b5 = (const float*)d_in[22];

    float* H0 = (float*)d_ws;                                  // [8][4096][64] f32 = 8 MB
    uint32_t* gmax = (uint32_t*)((char*)d_ws + (size_t)NB * NPTS * 64 * 4);  // [8][128] u32

    hipMemsetAsync(gmax, 0, NB * 128 * sizeof(uint32_t), stream);  // enc(-inf) floor

    k1_knn_edge<<<dim3(344), dim3(768), 0, stream>>>(x, W0, b0, s0, t0, H0);
    k2_mlp<<<dim3(1024), dim3(128), 0, stream>>>(H0, W1, b1, s1, t1,
                                                 W2, b2, s2, t2,
                                                 W3, b3, s3, t3, gmax);
    k3_head<<<dim3(64), dim3(256), 0, stream>>>(gmax, W4, b4, s4, t4, W5, b5,
                                                (float*)d_out);
}

// Round 15
// 155.834 us; speedup vs baseline: 1.0564x; 1.0564x over previous
//
#include <hip/hip_runtime.h>
#include <hip/hip_bf16.h>
#include <cstdint>

#define NPTS 4096
#define NB 8
#define KNN 20
#define CAP 40          // collected-candidate capacity (n ~20-24; 40 = big slack)

__device__ __forceinline__ float lrelu(float x) { return x >= 0.0f ? x : 0.2f * x; }

// monotone float<->uint mapping (order-preserving for all finite floats)
__device__ __forceinline__ uint32_t enc_f32(float f) {
    uint32_t u = __float_as_uint(f);
    return (u & 0x80000000u) ? ~u : (u | 0x80000000u);
}
__device__ __forceinline__ float dec_f32(uint32_t u) {
    return (u & 0x80000000u) ? __uint_as_float(u ^ 0x80000000u) : __uint_as_float(~u);
}

// XOR bank swizzle (verified R8: bank conflicts 110K -> 0 in both patterns)
__device__ __forceinline__ int physidx(int i) {
    return (i & ~63) | ((i ^ (i >> 6)) & 63);
}

// ---------------------------------------------------------------------------
// K1: fused kNN (top-20 smallest sq-dist, ties -> smaller index) + EdgeConv
//     (6->64) + max over k.  R11 configuration verbatim (measured 90.6 us):
//     512-thr blocks, 512 blocks (2 resident/CU), 8 rows/wave, full LDS
//     persist, fmed3 top-2 insert, 16-bit radix theta~, cooperative collect.
// ---------------------------------------------------------------------------
__global__ __launch_bounds__(512, 4) void k1_knn_edge(
        const float* __restrict__ x,
        const float* __restrict__ W0, const float* __restrict__ b0,
        const float* __restrict__ s0, const float* __restrict__ t0,
        float* __restrict__ H0)
{
    __shared__ float4 pts[NPTS];          // 64 KB, swizzled, (2x,2y,2z,-|p|^2)
    __shared__ float  cval[8][4][CAP];    // 5 KB
    __shared__ int    cidx[8][4][CAP];    // 5 KB
    __shared__ int    sel[8][4][KNN];     // 2.5 KB
    __shared__ float  sW0[64 * 6];
    __shared__ float  sB[64], sS[64], sT[64];

    const int blk = blockIdx.x;
    const int b = blk >> 6;               // 64 blocks per batch
    const int rowbase = (blk & 63) << 6;  // 64 rows per block
    const int t = threadIdx.x;
    const int lane = t & 63;
    const int w = t >> 6;                 // wave 0..7

    const float* xb = x + (size_t)b * (NPTS * 3);

    // ---- single staging of all 4096 points ----
    for (int i = t; i < NPTS; i += 512) {
        float x0 = xb[3 * i], x1 = xb[3 * i + 1], x2 = xb[3 * i + 2];
        float pp = __fadd_rn(__fadd_rn(__fmul_rn(x0, x0), __fmul_rn(x1, x1)),
                             __fmul_rn(x2, x2));
        pts[physidx(i)] = make_float4(x0 + x0, x1 + x1, x2 + x2, -pp);
    }
    if (t < 64) {
        #pragma unroll
        for (int c = 0; c < 6; c++) sW0[t * 6 + c] = W0[t * 6 + c];
        sB[t] = b0[t]; sS[t] = s0[t]; sT[t] = t0[t];
    }

    const int r0 = rowbase + w * 8;
    float qx[8], qy[8], qz[8];
    #pragma unroll
    for (int rr = 0; rr < 8; rr++) {
        qx[rr] = xb[3 * (r0 + rr) + 0];
        qy[rr] = xb[3 * (r0 + rr) + 1];
        qz[rr] = xb[3 * (r0 + rr) + 2];
    }
    __syncthreads();

    // ---- P1: per-lane top-2 values for 8 rows ----
    float l0[8], l1[8];
    #pragma unroll
    for (int rr = 0; rr < 8; rr++) { l0[rr] = -INFINITY; l1[rr] = -INFINITY; }

    #pragma unroll 4
    for (int j = 0; j < 64; j++) {
        const float4 p = pts[(j << 6) | ((lane ^ j) & 63)];
        #pragma unroll
        for (int rr = 0; rr < 8; rr++) {
            float u = fmaf(qx[rr], p.x, fmaf(qy[rr], p.y, fmaf(qz[rr], p.z, p.w)));
            l1[rr] = __builtin_amdgcn_fmed3f(u, l0[rr], l1[rr]);  // new top-2
            l0[rr] = fmaxf(u, l0[rr]);                            // new top-1
        }
    }

    const float wa0 = sW0[lane * 6 + 0], wa1 = sW0[lane * 6 + 1], wa2 = sW0[lane * 6 + 2];
    const float wa0h = 0.5f * wa0, wa1h = 0.5f * wa1, wa2h = 0.5f * wa2;  // pts hold 2p
    const float wd0 = sW0[lane * 6 + 3] - wa0;
    const float wd1 = sW0[lane * 6 + 4] - wa1;
    const float wd2 = sW0[lane * 6 + 5] - wa2;

    // ---- process rows in two halves of 4 (keeps collect-LDS small) ----
    for (int half = 0; half < 2; half++) {
        const int R = half * 4;

        // P2: 16-bit radix-ballot theta~ (bits 31..16 of enc).
        uint32_t e0[4], e1[4], pr[4];
        #pragma unroll
        for (int rr = 0; rr < 4; rr++) {
            e0[rr] = enc_f32(l0[R + rr]);
            e1[rr] = enc_f32(l1[R + rr]);
            pr[rr] = 0u;
        }
        for (int bit = 31; bit >= 16; bit--) {
            #pragma unroll
            for (int rr = 0; rr < 4; rr++) {
                uint32_t T = pr[rr] | (1u << bit);
                int c = __popcll(__ballot(e0[rr] >= T)) + __popcll(__ballot(e1[rr] >= T));
                if (c >= KNN) pr[rr] = T;     // wave-uniform
            }
        }
        float th[4];
        #pragma unroll
        for (int rr = 0; rr < 4; rr++) th[rr] = dec_f32(pr[rr]);

        // P3a: collect all u >= theta~ via cooperative lane-rescans.
        int nsel[4];
        #pragma unroll
        for (int rr = 0; rr < 4; rr++) {
            int base = 0;
            unsigned long long lm = __ballot(l0[R + rr] >= th[rr]);
            while (lm) {
                int L = __ffsll(lm) - 1; lm &= lm - 1;          // uniform
                const float4 p = pts[(lane << 6) | ((L ^ lane) & 63)];
                float u = fmaf(qx[R + rr], p.x,
                          fmaf(qy[R + rr], p.y, fmaf(qz[R + rr], p.z, p.w)));
                unsigned long long hit = __ballot(u >= th[rr]);
                if (u >= th[rr]) {
                    int pos = base + __popcll(hit & ((1ull << lane) - 1ull));
                    if (pos < CAP) {
                        cval[w][rr][pos] = u;
                        cidx[w][rr][pos] = (lane << 6) | L;
                    }
                }
                base += __popcll(hit);
            }
            nsel[rr] = min(base, CAP);
        }

        // P3b: exact top-20 by (value desc, idx asc) when n > 20
        #pragma unroll
        for (int rr = 0; rr < 4; rr++) {
            int n = nsel[rr];
            if (n > KNN) {                    // wave-uniform branch
                bool act = lane < n;
                float ve = act ? cval[w][rr][lane] : -INFINITY;
                int   ie = act ? cidx[w][rr][lane] : 0x7FFFFFFF;
                int rk = 0;
                for (int f = 0; f < n; f++) {
                    float vf = cval[w][rr][f];
                    int   if_ = cidx[w][rr][f];
                    rk += ((vf > ve) || (vf == ve && if_ < ie)) ? 1 : 0;
                }
                if (act && rk < KNN) sel[w][rr][rk] = ie;
            }
        }

        // P3c: consume -- per-channel (lane) max over selected neighbors
        #pragma unroll
        for (int rr = 0; rr < 4; rr++) {
            int n = nsel[rr];
            bool ranked = n > KNN;
            int cnt20 = ranked ? KNN : n;
            float mm = -INFINITY;
            for (int e = 0; e < cnt20; e++) {
                int g = ranked ? sel[w][rr][e] : cidx[w][rr][e];   // uniform
                float4 p = pts[physidx(g)];
                float dotp = fmaf(wa2h, p.z, fmaf(wa1h, p.y, wa0h * p.x));
                mm = fmaxf(mm, dotp);
            }
            // conv = max_k(W0a.p_k) + (W0b-W0a).q ; (conv+b)*s+t ; lrelu.
            // s0>0 and lrelu monotone => max commutes past affine+activation.
            float cterm = fmaf(wd2, qz[R + rr], fmaf(wd1, qy[R + rr], wd0 * qx[R + rr]));
            float z = (mm + cterm + sB[lane]) * sS[lane] + sT[lane];
            H0[((size_t)(b * NPTS) + r0 + R + rr) * 64 + lane] = lrelu(z);
        }
    }
}

// ---------------------------------------------------------------------------
// K2: pconv chain 64->64->128->128 + max over points.  512 blocks x 128 thr,
//     64-pt tiles, 8 points per thread (2x the R9 weight-load amortization,
//     8 independent fma chains per load).  Weights from global (L2-cached);
//     h tiles in LDS (~52 KB -> 3 blocks/CU).
//     Thread = (ps 0..7, og 0..15); points {ps + 8*pp, pp=0..7}.
// ---------------------------------------------------------------------------
__global__ __launch_bounds__(128, 2) void k2_mlp(
        const float* __restrict__ H0,
        const float* __restrict__ W1, const float* __restrict__ b1,
        const float* __restrict__ s1, const float* __restrict__ t1,
        const float* __restrict__ W2, const float* __restrict__ b2,
        const float* __restrict__ s2, const float* __restrict__ t2,
        const float* __restrict__ W3, const float* __restrict__ b3,
        const float* __restrict__ s3, const float* __restrict__ t3,
        uint32_t* __restrict__ gmax)
{
    __shared__ float A[64 * 132];     // h0 (64c) then aliased h2 (128c), stride 132
    __shared__ float h1[64 * 68];     // stride 68
    __shared__ uint32_t bmax[128];

    const int t = threadIdx.x;            // 128 threads
    const int blk = blockIdx.x;
    const int b = blk >> 6;               // 64 blocks per batch
    const int pbase = (blk & 63) * 64;    // 64 points per block

    const int ps = t & 7;                 // 0..7
    const int og = t >> 3;                // 0..15

    // stage h0 tile [64 pts][64 ch] -> A (stride 132): 1024 float4, 8/thread
    {
        const float4* src = (const float4*)&H0[((size_t)(b * NPTS) + pbase) * 64];
        #pragma unroll
        for (int k = 0; k < 8; k++) {
            int i4 = t * 8 + k;
            int p = i4 >> 4, c = (i4 & 15) * 4;
            *(float4*)&A[p * 132 + c] = src[i4];
        }
    }
    bmax[t] = 0u;
    __syncthreads();

    // ---- L1: 64 -> 64 ; outs o = og*4+[0,4), pts {ps+8*pp} ----
    {
        float acc[8][4] = {};
        for (int c = 0; c < 64; c += 4) {
            float4 h[8];
            #pragma unroll
            for (int pp = 0; pp < 8; pp++)
                h[pp] = *(const float4*)&A[(ps + 8 * pp) * 132 + c];
            #pragma unroll
            for (int r = 0; r < 4; r++) {
                float4 wv = *(const float4*)&W1[(og * 4 + r) * 64 + c];
                #pragma unroll
                for (int pp = 0; pp < 8; pp++)
                    acc[pp][r] += h[pp].x * wv.x + h[pp].y * wv.y
                                + h[pp].z * wv.z + h[pp].w * wv.w;
            }
        }
        #pragma unroll
        for (int pp = 0; pp < 8; pp++) {
            float4 o4; float* po = (float*)&o4;
            #pragma unroll
            for (int r = 0; r < 4; r++) {
                int o = og * 4 + r;
                po[r] = lrelu((acc[pp][r] + b1[o]) * s1[o] + t1[o]);
            }
            *(float4*)&h1[(ps + 8 * pp) * 68 + og * 4] = o4;
        }
    }
    __syncthreads();

    // ---- L2: 64 -> 128 ; outs o = og*8+[0,8) ; h2 overwrites A ----
    {
        float acc[8][8] = {};
        for (int c = 0; c < 64; c += 4) {
            float4 h[8];
            #pragma unroll
            for (int pp = 0; pp < 8; pp++)
                h[pp] = *(const float4*)&h1[(ps + 8 * pp) * 68 + c];
            #pragma unroll
            for (int r = 0; r < 8; r++) {
                float4 wv = *(const float4*)&W2[(og * 8 + r) * 64 + c];
                #pragma unroll
                for (int pp = 0; pp < 8; pp++)
                    acc[pp][r] += h[pp].x * wv.x + h[pp].y * wv.y
                                + h[pp].z * wv.z + h[pp].w * wv.w;
            }
        }
        __syncthreads();   // everyone done reading A (h0) before overwriting
        #pragma unroll
        for (int pp = 0; pp < 8; pp++) {
            float4 o4a, o4b; float* pa = (float*)&o4a; float* pb = (float*)&o4b;
            #pragma unroll
            for (int r = 0; r < 4; r++) {
                int o = og * 8 + r;
                pa[r] = lrelu((acc[pp][r] + b2[o]) * s2[o] + t2[o]);
            }
            #pragma unroll
            for (int r = 4; r < 8; r++) {
                int o = og * 8 + r;
                pb[r - 4] = lrelu((acc[pp][r] + b2[o]) * s2[o] + t2[o]);
            }
            *(float4*)&A[(ps + 8 * pp) * 132 + og * 8]     = o4a;
            *(float4*)&A[(ps + 8 * pp) * 132 + og * 8 + 4] = o4b;
        }
    }
    __syncthreads();

    // ---- L3: 128 -> 128 + max over points ----
    {
        float acc[8][8] = {};
        for (int c = 0; c < 128; c += 4) {
            float4 h[8];
            #pragma unroll
            for (int pp = 0; pp < 8; pp++)
                h[pp] = *(const float4*)&A[(ps + 8 * pp) * 132 + c];
            #pragma unroll
            for (int r = 0; r < 8; r++) {
                float4 wv = *(const float4*)&W3[(og * 8 + r) * 128 + c];
                #pragma unroll
                for (int pp = 0; pp < 8; pp++)
                    acc[pp][r] += h[pp].x * wv.x + h[pp].y * wv.y
                                + h[pp].z * wv.z + h[pp].w * wv.w;
            }
        }
        // max over own 8 points (pre-affine: s3>0, monotone), then across ps
        float m[8];
        #pragma unroll
        for (int r = 0; r < 8; r++) {
            float m01 = fmaxf(acc[0][r], acc[1][r]);
            float m23 = fmaxf(acc[2][r], acc[3][r]);
            float m45 = fmaxf(acc[4][r], acc[5][r]);
            float m67 = fmaxf(acc[6][r], acc[7][r]);
            m[r] = fmaxf(fmaxf(m01, m23), fmaxf(m45, m67));
        }
        #pragma unroll
        for (int off = 1; off < 8; off <<= 1) {
            #pragma unroll
            for (int r = 0; r < 8; r++)
                m[r] = fmaxf(m[r], __shfl_xor(m[r], off));
        }
        if (ps == 0) {
            #pragma unroll
            for (int r = 0; r < 8; r++) {
                int o = og * 8 + r;
                float z = lrelu((m[r] + b3[o]) * s3[o] + t3[o]);
                atomicMax(&bmax[o], enc_f32(z));
            }
        }
    }
    __syncthreads();
    atomicMax(&gmax[b * 128 + t], bmax[t]);
}

// ---------------------------------------------------------------------------
// K3: head 128 -> 512 (affine+lrelu) -> 1024.  64 blocks (8 batch x 8 chunk).
// ---------------------------------------------------------------------------
__global__ __launch_bounds__(256) void k3_head(
        const uint32_t* __restrict__ gmax,
        const float* __restrict__ W4, const float* __restrict__ b4,
        const float* __restrict__ s4, const float* __restrict__ t4,
        const float* __restrict__ W5, const float* __restrict__ b5,
        float* __restrict__ out)
{
    __shared__ float sIn[128];
    __shared__ float sH4[512];
    const int t = threadIdx.x;
    const int b = blockIdx.x >> 3;
    const int chunk = blockIdx.x & 7;

    if (t < 128) sIn[t] = dec_f32(gmax[b * 128 + t]);
    __syncthreads();

    #pragma unroll
    for (int rep = 0; rep < 2; rep++) {
        int o = t + rep * 256;
        const float4* wr = (const float4*)&W4[(size_t)o * 128];
        float acc = 0.f;
        for (int c4 = 0; c4 < 32; c4++) {
            float4 wv = wr[c4];
            acc += sIn[c4 * 4] * wv.x + sIn[c4 * 4 + 1] * wv.y
                 + sIn[c4 * 4 + 2] * wv.z + sIn[c4 * 4 + 3] * wv.w;
        }
        float z = (acc + b4[o]) * s4[o] + t4[o];
        sH4[o] = lrelu(z);
    }
    __syncthreads();

    if (t < 128) {
        int o = chunk * 128 + t;
        const float4* wr = (const float4*)&W5[(size_t)o * 512];
        float acc = 0.f;
        for (int c4 = 0; c4 < 128; c4++) {
            float4 wv = wr[c4];
            acc += sH4[c4 * 4] * wv.x + sH4[c4 * 4 + 1] * wv.y
                 + sH4[c4 * 4 + 2] * wv.z + sH4[c4 * 4 + 3] * wv.w;
        }
        out[(size_t)b * 1024 + o] = acc + b5[o];
    }
}

// ---------------------------------------------------------------------------
extern "C" void kernel_launch(void* const* d_in, const int* in_sizes, int n_in,
                              void* d_out, int out_size, void* d_ws, size_t ws_size,
                              hipStream_t stream) {
    (void)in_sizes; (void)n_in; (void)out_size; (void)ws_size;
    const float* x  = (const float*)d_in[0];
    const float* W0 = (const float*)d_in[1];
    const float* b0 = (const float*)d_in[2];
    const float* s0 = (const float*)d_in[3];
    const float* t0 = (const float*)d_in[4];
    const float* W1 = (const float*)d_in[5];
    const float* b1 = (const float*)d_in[6];
    const float* s1 = (const float*)d_in[7];
    const float* t1 = (const float*)d_in[8];
    const float* W2 = (const float*)d_in[9];
    const float* b2 = (const float*)d_in[10];
    const float* s2 = (const float*)d_in[11];
    const float* t2 = (const float*)d_in[12];
    const float* W3 = (const float*)d_in[13];
    const float* b3 = (const float*)d_in[14];
    const float* s3 = (const float*)d_in[15];
    const float* t3 = (const float*)d_in[16];
    const float* W4 = (const float*)d_in[17];
    const float* b4 = (const float*)d_in[18];
    const float* s4 = (const float*)d_in[19];
    const float* t4 = (const float*)d_in[20];
    const float* W5 = (const float*)d_in[21];
    const float* b5 = (const float*)d_in[22];

    float* H0 = (float*)d_ws;                                  // [8][4096][64] f32 = 8 MB
    uint32_t* gmax = (uint32_t*)((char*)d_ws + (size_t)NB * NPTS * 64 * 4);  // [8][128] u32

    hipMemsetAsync(gmax, 0, NB * 128 * sizeof(uint32_t), stream);  // enc(-inf) floor

    k1_knn_edge<<<dim3(512), dim3(512), 0, stream>>>(x, W0, b0, s0, t0, H0);
    k2_mlp<<<dim3(512), dim3(128), 0, stream>>>(H0, W1, b1, s1, t1,
                                                W2, b2, s2, t2,
                                                W3, b3, s3, t3, gmax);
    k3_head<<<dim3(64), dim3(256), 0, stream>>>(gmax, W4, b4, s4, t4, W5, b5,
                                                (float*)d_out);
}

// Round 16
// 132.488 us; speedup vs baseline: 1.2425x; 1.1762x over previous
//
#include <hip/hip_runtime.h>
#include <hip/hip_bf16.h>
#include <cstdint>

#define NPTS 4096
#define NB 8
#define KNN 20
#define CAP 40

// LDS union layout (bytes): [0,64K) pts  ->  reused as A[64][132] + h1[64][68]
#define CVAL_OFF 65536
#define CIDX_OFF (CVAL_OFF + 8 * 4 * CAP * 4)
#define SEL_OFF  (CIDX_OFF + 8 * 4 * CAP * 4)
#define SMEM_SZ  (SEL_OFF + 8 * 4 * KNN * 4)     // 78336 B
#define H1_OFF   33792                            // 64*132*4

__device__ __forceinline__ float lrelu(float x) { return x >= 0.0f ? x : 0.2f * x; }

__device__ __forceinline__ uint32_t enc_f32(float f) {
    uint32_t u = __float_as_uint(f);
    return (u & 0x80000000u) ? ~u : (u | 0x80000000u);
}
__device__ __forceinline__ float dec_f32(uint32_t u) {
    return (u & 0x80000000u) ? __uint_as_float(u ^ 0x80000000u) : __uint_as_float(~u);
}

// XOR bank swizzle (verified R8: conflicts 110K -> 0 in both access patterns)
__device__ __forceinline__ int physidx(int i) {
    return (i & ~63) | ((i ^ (i >> 6)) & 63);
}

// ---------------------------------------------------------------------------
// K1: fused kNN + EdgeConv + max-k  +  pconv chain 64->64->128->128 + max-pts.
//     kNN part = R11 config verbatim (measured 90.6us).  After the selection
//     phases, pts/collect LDS is dead -> reused for the MLP tiles (A, h1);
//     h0 carried in 8 registers across the phase boundary.  MLP shape = R9's
//     measured-best (4 pts/thread, og-group broadcast weight loads).
// ---------------------------------------------------------------------------
__global__ __launch_bounds__(512, 4) void k1_fused(
        const float* __restrict__ x,
        const float* __restrict__ W0, const float* __restrict__ b0,
        const float* __restrict__ s0, const float* __restrict__ t0,
        const float* __restrict__ W1, const float* __restrict__ b1,
        const float* __restrict__ s1, const float* __restrict__ t1,
        const float* __restrict__ W2, const float* __restrict__ b2,
        const float* __restrict__ s2, const float* __restrict__ t2,
        const float* __restrict__ W3, const float* __restrict__ b3,
        const float* __restrict__ s3, const float* __restrict__ t3,
        uint32_t* __restrict__ gmax)
{
    __shared__ alignas(16) char smem[SMEM_SZ];
    __shared__ float sW0[64 * 6];
    __shared__ float sB[64], sS[64], sT[64];
    __shared__ uint32_t bmax[128];

    float4* pts = (float4*)smem;

    const int blk = blockIdx.x;
    const int b = blk >> 6;               // 64 blocks per batch
    const int rowbase = (blk & 63) << 6;  // 64 rows per block
    const int t = threadIdx.x;
    const int lane = t & 63;
    const int w = t >> 6;                 // wave 0..7

    const float* xb = x + (size_t)b * (NPTS * 3);

    // ---- single staging of all 4096 points ----
    for (int i = t; i < NPTS; i += 512) {
        float x0 = xb[3 * i], x1 = xb[3 * i + 1], x2 = xb[3 * i + 2];
        float pp = __fadd_rn(__fadd_rn(__fmul_rn(x0, x0), __fmul_rn(x1, x1)),
                             __fmul_rn(x2, x2));
        pts[physidx(i)] = make_float4(x0 + x0, x1 + x1, x2 + x2, -pp);
    }
    if (t < 64) {
        #pragma unroll
        for (int c = 0; c < 6; c++) sW0[t * 6 + c] = W0[t * 6 + c];
        sB[t] = b0[t]; sS[t] = s0[t]; sT[t] = t0[t];
    }
    if (t < 128) bmax[t] = 0u;

    const int r0 = rowbase + w * 8;
    float qx[8], qy[8], qz[8];
    #pragma unroll
    for (int rr = 0; rr < 8; rr++) {
        qx[rr] = xb[3 * (r0 + rr) + 0];
        qy[rr] = xb[3 * (r0 + rr) + 1];
        qz[rr] = xb[3 * (r0 + rr) + 2];
    }
    __syncthreads();

    // ---- P1: per-lane top-2 values for 8 rows ----
    float l0[8], l1v[8];
    #pragma unroll
    for (int rr = 0; rr < 8; rr++) { l0[rr] = -INFINITY; l1v[rr] = -INFINITY; }

    #pragma unroll 4
    for (int j = 0; j < 64; j++) {
        const float4 p = pts[(j << 6) | ((lane ^ j) & 63)];
        #pragma unroll
        for (int rr = 0; rr < 8; rr++) {
            float u = fmaf(qx[rr], p.x, fmaf(qy[rr], p.y, fmaf(qz[rr], p.z, p.w)));
            l1v[rr] = __builtin_amdgcn_fmed3f(u, l0[rr], l1v[rr]);
            l0[rr] = fmaxf(u, l0[rr]);
        }
    }

    const float wa0 = sW0[lane * 6 + 0], wa1 = sW0[lane * 6 + 1], wa2 = sW0[lane * 6 + 2];
    const float wa0h = 0.5f * wa0, wa1h = 0.5f * wa1, wa2h = 0.5f * wa2;  // pts hold 2p
    const float wd0 = sW0[lane * 6 + 3] - wa0;
    const float wd1 = sW0[lane * 6 + 4] - wa1;
    const float wd2 = sW0[lane * 6 + 5] - wa2;

    float* cvalb = (float*)(smem + CVAL_OFF);
    int*   cidxb = (int*)(smem + CIDX_OFF);
    int*   selb  = (int*)(smem + SEL_OFF);

    float hz[8];   // h0 output, carried in registers across the LDS reuse

    for (int half = 0; half < 2; half++) {
        const int R = half * 4;

        // P2: 16-bit radix-ballot theta~
        uint32_t e0[4], e1[4], pr[4];
        #pragma unroll
        for (int rr = 0; rr < 4; rr++) {
            e0[rr] = enc_f32(l0[R + rr]);
            e1[rr] = enc_f32(l1v[R + rr]);
            pr[rr] = 0u;
        }
        for (int bit = 31; bit >= 16; bit--) {
            #pragma unroll
            for (int rr = 0; rr < 4; rr++) {
                uint32_t T = pr[rr] | (1u << bit);
                int c = __popcll(__ballot(e0[rr] >= T)) + __popcll(__ballot(e1[rr] >= T));
                if (c >= KNN) pr[rr] = T;
            }
        }
        float th[4];
        #pragma unroll
        for (int rr = 0; rr < 4; rr++) th[rr] = dec_f32(pr[rr]);

        // P3a: cooperative collect
        int nsel[4];
        #pragma unroll
        for (int rr = 0; rr < 4; rr++) {
            float* cval = cvalb + (w * 4 + rr) * CAP;
            int*   cidx = cidxb + (w * 4 + rr) * CAP;
            int base = 0;
            unsigned long long lm = __ballot(l0[R + rr] >= th[rr]);
            while (lm) {
                int L = __ffsll(lm) - 1; lm &= lm - 1;
                const float4 p = pts[(lane << 6) | ((L ^ lane) & 63)];
                float u = fmaf(qx[R + rr], p.x,
                          fmaf(qy[R + rr], p.y, fmaf(qz[R + rr], p.z, p.w)));
                unsigned long long hit = __ballot(u >= th[rr]);
                if (u >= th[rr]) {
                    int pos = base + __popcll(hit & ((1ull << lane) - 1ull));
                    if (pos < CAP) { cval[pos] = u; cidx[pos] = (lane << 6) | L; }
                }
                base += __popcll(hit);
            }
            nsel[rr] = min(base, CAP);
        }

        // P3b: exact top-20 when n > 20
        #pragma unroll
        for (int rr = 0; rr < 4; rr++) {
            int n = nsel[rr];
            if (n > KNN) {
                float* cval = cvalb + (w * 4 + rr) * CAP;
                int*   cidx = cidxb + (w * 4 + rr) * CAP;
                int*   sel  = selb  + (w * 4 + rr) * KNN;
                bool act = lane < n;
                float ve = act ? cval[lane] : -INFINITY;
                int   ie = act ? cidx[lane] : 0x7FFFFFFF;
                int rk = 0;
                for (int f = 0; f < n; f++) {
                    float vf = cval[f];
                    int   if_ = cidx[f];
                    rk += ((vf > ve) || (vf == ve && if_ < ie)) ? 1 : 0;
                }
                if (act && rk < KNN) sel[rk] = ie;
            }
        }

        // P3c: consume -> hz (no global write)
        #pragma unroll
        for (int rr = 0; rr < 4; rr++) {
            int n = nsel[rr];
            bool ranked = n > KNN;
            int cnt20 = ranked ? KNN : n;
            const float* cval = cvalb + (w * 4 + rr) * CAP;
            const int*   cidx = cidxb + (w * 4 + rr) * CAP;
            const int*   sel  = selb  + (w * 4 + rr) * KNN;
            (void)cval;
            float mm = -INFINITY;
            for (int e = 0; e < cnt20; e++) {
                int g = ranked ? sel[e] : cidx[e];
                float4 p = pts[physidx(g)];
                float dotp = fmaf(wa2h, p.z, fmaf(wa1h, p.y, wa0h * p.x));
                mm = fmaxf(mm, dotp);
            }
            float cterm = fmaf(wd2, qz[R + rr], fmaf(wd1, qy[R + rr], wd0 * qx[R + rr]));
            float z = (mm + cterm + sB[lane]) * sS[lane] + sT[lane];
            hz[R + rr] = lrelu(z);
        }
    }

    // ================= MLP phase: reuse LDS =================
    __syncthreads();     // pts + collect arrays now dead
    float* A  = (float*)smem;            // [64][132]: h0 (64c) then h2 (128c)
    float* h1 = (float*)(smem + H1_OFF); // [64][68]

    {
        const int row = w * 8;
        #pragma unroll
        for (int rr = 0; rr < 8; rr++) A[(row + rr) * 132 + lane] = hz[rr];
    }
    __syncthreads();

    const int ps = t & 15;   // 16 point-slots, 4 pts each: {ps, ps+16, ps+32, ps+48}
    const int og = t >> 4;   // 0..31

    // ---- L1: 64 -> 64 ; outs o = og*2+[0,2) ----
    {
        float acc[4][2] = {};
        for (int c = 0; c < 64; c += 4) {
            float4 h[4];
            #pragma unroll
            for (int pp = 0; pp < 4; pp++)
                h[pp] = *(const float4*)&A[(ps + 16 * pp) * 132 + c];
            #pragma unroll
            for (int r = 0; r < 2; r++) {
                float4 wv = *(const float4*)&W1[(og * 2 + r) * 64 + c];
                #pragma unroll
                for (int pp = 0; pp < 4; pp++)
                    acc[pp][r] += h[pp].x * wv.x + h[pp].y * wv.y
                                + h[pp].z * wv.z + h[pp].w * wv.w;
            }
        }
        #pragma unroll
        for (int r = 0; r < 2; r++) {
            int o = og * 2 + r;
            float bb = b1[o], ss = s1[o], tt = t1[o];
            #pragma unroll
            for (int pp = 0; pp < 4; pp++)
                h1[(ps + 16 * pp) * 68 + o] = lrelu((acc[pp][r] + bb) * ss + tt);
        }
    }
    __syncthreads();

    // ---- L2: 64 -> 128 ; outs o = og*4+[0,4) ; h2 overwrites A ----
    {
        float acc[4][4] = {};
        for (int c = 0; c < 64; c += 4) {
            float4 h[4];
            #pragma unroll
            for (int pp = 0; pp < 4; pp++)
                h[pp] = *(const float4*)&h1[(ps + 16 * pp) * 68 + c];
            #pragma unroll
            for (int r = 0; r < 4; r++) {
                float4 wv = *(const float4*)&W2[(og * 4 + r) * 64 + c];
                #pragma unroll
                for (int pp = 0; pp < 4; pp++)
                    acc[pp][r] += h[pp].x * wv.x + h[pp].y * wv.y
                                + h[pp].z * wv.z + h[pp].w * wv.w;
            }
        }
        __syncthreads();   // all L1-era reads of A done before overwrite
        #pragma unroll
        for (int pp = 0; pp < 4; pp++) {
            float4 o4; float* po = (float*)&o4;
            #pragma unroll
            for (int r = 0; r < 4; r++) {
                int o = og * 4 + r;
                po[r] = lrelu((acc[pp][r] + b2[o]) * s2[o] + t2[o]);
            }
            *(float4*)&A[(ps + 16 * pp) * 132 + og * 4] = o4;
        }
    }
    __syncthreads();

    // ---- L3: 128 -> 128 + max over the block's 64 points ----
    {
        float acc[4][4] = {};
        for (int c = 0; c < 128; c += 4) {
            float4 h[4];
            #pragma unroll
            for (int pp = 0; pp < 4; pp++)
                h[pp] = *(const float4*)&A[(ps + 16 * pp) * 132 + c];
            #pragma unroll
            for (int r = 0; r < 4; r++) {
                float4 wv = *(const float4*)&W3[(og * 4 + r) * 128 + c];
                #pragma unroll
                for (int pp = 0; pp < 4; pp++)
                    acc[pp][r] += h[pp].x * wv.x + h[pp].y * wv.y
                                + h[pp].z * wv.z + h[pp].w * wv.w;
            }
        }
        float m[4];
        #pragma unroll
        for (int r = 0; r < 4; r++)
            m[r] = fmaxf(fmaxf(acc[0][r], acc[1][r]), fmaxf(acc[2][r], acc[3][r]));
        #pragma unroll
        for (int off = 1; off < 16; off <<= 1) {
            #pragma unroll
            for (int r = 0; r < 4; r++)
                m[r] = fmaxf(m[r], __shfl_xor(m[r], off));
        }
        if (ps == 0) {
            #pragma unroll
            for (int r = 0; r < 4; r++) {
                int o = og * 4 + r;
                float z = lrelu((m[r] + b3[o]) * s3[o] + t3[o]);
                atomicMax(&bmax[o], enc_f32(z));
            }
        }
    }
    __syncthreads();
    if (t < 128) atomicMax(&gmax[b * 128 + t], bmax[t]);
}

// ---------------------------------------------------------------------------
// K3: head 128 -> 512 (affine+lrelu) -> 1024.  64 blocks (8 batch x 8 chunk).
// ---------------------------------------------------------------------------
__global__ __launch_bounds__(256) void k3_head(
        const uint32_t* __restrict__ gmax,
        const float* __restrict__ W4, const float* __restrict__ b4,
        const float* __restrict__ s4, const float* __restrict__ t4,
        const float* __restrict__ W5, const float* __restrict__ b5,
        float* __restrict__ out)
{
    __shared__ float sIn[128];
    __shared__ float sH4[512];
    const int t = threadIdx.x;
    const int b = blockIdx.x >> 3;
    const int chunk = blockIdx.x & 7;

    if (t < 128) sIn[t] = dec_f32(gmax[b * 128 + t]);
    __syncthreads();

    #pragma unroll
    for (int rep = 0; rep < 2; rep++) {
        int o = t + rep * 256;
        const float4* wr = (const float4*)&W4[(size_t)o * 128];
        float acc = 0.f;
        for (int c4 = 0; c4 < 32; c4++) {
            float4 wv = wr[c4];
            acc += sIn[c4 * 4] * wv.x + sIn[c4 * 4 + 1] * wv.y
                 + sIn[c4 * 4 + 2] * wv.z + sIn[c4 * 4 + 3] * wv.w;
        }
        float z = (acc + b4[o]) * s4[o] + t4[o];
        sH4[o] = lrelu(z);
    }
    __syncthreads();

    if (t < 128) {
        int o = chunk * 128 + t;
        const float4* wr = (const float4*)&W5[(size_t)o * 512];
        float acc = 0.f;
        for (int c4 = 0; c4 < 128; c4++) {
            float4 wv = wr[c4];
            acc += sH4[c4 * 4] * wv.x + sH4[c4 * 4 + 1] * wv.y
                 + sH4[c4 * 4 + 2] * wv.z + sH4[c4 * 4 + 3] * wv.w;
        }
        out[(size_t)b * 1024 + o] = acc + b5[o];
    }
}

// ---------------------------------------------------------------------------
extern "C" void kernel_launch(void* const* d_in, const int* in_sizes, int n_in,
                              void* d_out, int out_size, void* d_ws, size_t ws_size,
                              hipStream_t stream) {
    (void)in_sizes; (void)n_in; (void)out_size; (void)ws_size;
    const float* x  = (const float*)d_in[0];
    const float* W0 = (const float*)d_in[1];
    const float* b0 = (const float*)d_in[2];
    const float* s0 = (const float*)d_in[3];
    const float* t0 = (const float*)d_in[4];
    const float* W1 = (const float*)d_in[5];
    const float* b1 = (const float*)d_in[6];
    const float* s1 = (const float*)d_in[7];
    const float* t1 = (const float*)d_in[8];
    const float* W2 = (const float*)d_in[9];
    const float* b2 = (const float*)d_in[10];
    const float* s2 = (const float*)d_in[11];
    const float* t2 = (const float*)d_in[12];
    const float* W3 = (const float*)d_in[13];
    const float* b3 = (const float*)d_in[14];
    const float* s3 = (const float*)d_in[15];
    const float* t3 = (const float*)d_in[16];
    const float* W4 = (const float*)d_in[17];
    const float* b4 = (const float*)d_in[18];
    const float* s4 = (const float*)d_in[19];
    const float* t4 = (const float*)d_in[20];
    const float* W5 = (const float*)d_in[21];
    const float* b5 = (const float*)d_in[22];

    uint32_t* gmax = (uint32_t*)d_ws;     // [8][128] u32

    hipMemsetAsync(gmax, 0, NB * 128 * sizeof(uint32_t), stream);  // enc(-inf) floor

    k1_fused<<<dim3(512), dim3(512), 0, stream>>>(
        x, W0, b0, s0, t0,
        W1, b1, s1, t1,
        W2, b2, s2, t2,
        W3, b3, s3, t3, gmax);
    k3_head<<<dim3(64), dim3(256), 0, stream>>>(gmax, W4, b4, s4, t4, W5, b5,
                                                (float*)d_out);
}